// Round 11
// baseline (392.295 us; speedup 1.0000x reference)
//
#include <hip/hip_runtime.h>
#include <cstdint>
#include <cstddef>

// Problem geometry
#define T_N   500
#define B_N   16
#define F_IN  6300
#define KW    198          // 198 words * 32 bits = 6336 (K padded)
#define KPAD  6336
#define H1    1024
#define H2    20
#define N2P   32           // gemm2 N padded 20 -> 32
#define M_N   8000         // T*B rows, m = t*16 + b
#define M_PADN 8064        // 63 * 128 = 126 * 64

// SLAYER constants
#define DD_C   0.36787944117144233f   // exp(-1)
#define CC_C   2.718281828459045f     // e / tau
#define THETA_C 10.0f
#define INV2048 4.8828125e-4f

typedef _Float16 half8 __attribute__((ext_vector_type(8)));
typedef __attribute__((ext_vector_type(4))) float f32x4;

__device__ __forceinline__ unsigned short f2h_bits(float x) {
    union { _Float16 h; unsigned short u; } c; c.h = (_Float16)x; return c.u;
}
__device__ __forceinline__ float h2f(unsigned short u) {
    union { _Float16 h; unsigned short u; } c; c.u = u; return (float)c.h;
}

// ---------------------------------------------------------------------------
// Kernel 1 (fused prep):
//   [0,6336)    : pack input spikes -> bits_t[kw][m], m=(t*16+b)
//   [6336,7360) : split w1 -> w1f[2][1024][6336] fp16 (term2 scaled 2^11)
//   [7360,7392) : split w2 -> w2f[2][32][1024] fp16
// ---------------------------------------------------------------------------
__global__ void prep_fused_k(const float* __restrict__ x,
                             const float* __restrict__ w1,
                             const float* __restrict__ w2,
                             uint32_t* __restrict__ bits_t,
                             unsigned short* __restrict__ w1f,
                             unsigned short* __restrict__ w2f) {
    const int bid = blockIdx.x;
    if (bid < 6336) {
        const int b    = bid & 15;
        const int tmp  = bid >> 4;         // 0..395
        const int w    = tmp % 198;
        const int tch2 = tmp / 198;        // 0..1
        const int t    = tch2 * 256 + threadIdx.x;   // 0..511
        if (t >= 504) return;
        const int m = t * 16 + b;
        uint32_t word = 0u;
        if (t < T_N) {
            const int fbase = w * 32;
            #pragma unroll
            for (int j = 0; j < 32; ++j) {
                const int f = fbase + j;
                float v = 0.f;
                if (f < F_IN) v = x[((size_t)b * F_IN + f) * T_N + t];
                word |= (v != 0.f ? 1u : 0u) << j;
            }
        }
        bits_t[(size_t)w * M_PADN + m] = word;
    } else if (bid < 6336 + 1024) {
        const int o = bid - 6336;
        #pragma unroll 1
        for (int it = 0; it < 25; ++it) {
            const int f = it * 256 + threadIdx.x;
            if (f >= KPAD) break;
            float w = (f < F_IN) ? w1[(size_t)o * F_IN + f] : 0.f;
            const unsigned short h1 = f2h_bits(w);
            const float r1 = w - h2f(h1);
            const unsigned short h2 = f2h_bits(r1 * 2048.0f);
            const size_t base = (size_t)o * KPAD + f;
            w1f[base]                     = h1;
            w1f[(size_t)H1 * KPAD + base] = h2;
        }
    } else {
        const int o = bid - 7360;          // 0..31
        #pragma unroll
        for (int it = 0; it < 4; ++it) {
            const int k = it * 256 + threadIdx.x;
            float w = (o < H2) ? w2[(size_t)o * H1 + k] : 0.f;
            const unsigned short h1 = f2h_bits(w);
            const float r1 = w - h2f(h1);
            const unsigned short h2 = f2h_bits(r1 * 2048.0f);
            const size_t base = (size_t)o * H1 + k;
            w2f[base]                    = h1;
            w2f[(size_t)N2P * H1 + base] = h2;
        }
    }
}

// ---------------------------------------------------------------------------
// Kernel 2: GEMM1 via MFMA fp16, 2-term split. Round-9 pipeline (dbuf +
//   plain __syncthreads; the counted-vmcnt graft of round 10 regressed),
//   OCCUPANCY-RESTRUCTURED: block 64m x 128n, wave tile 64m x 32n
//   -> acc[2][4][2] = 64 acc regs (half of round 9) -> 3 blocks/CU
//   (launch_bounds(256,3)), +50% waves/SIMD for latency hiding.
//   u1 bit-identical to round 9 (same split, k-order, accum order).
// ---------------------------------------------------------------------------
__global__ __launch_bounds__(256, 3)
void gemm1_mfma_k(const uint32_t* __restrict__ bits_t,
                  const unsigned short* __restrict__ w1f,
                  float* __restrict__ u1) {
    __shared__ uint32_t BsU[2][2 * 128 * 16];    // 32 KB : [buf][term][row][16 u32]

    const int tid  = threadIdx.x;
    const int lane = tid & 63;
    const int wave = tid >> 6;                // n split only
    const int n0 = blockIdx.x * 128;          // n-tile -> XCD-exclusive B panel
    const int m0 = blockIdx.y * 64;           // 126 m-tiles of 64
    const int l15 = lane & 15, g = lane >> 4;

    const unsigned short* bsrc0 =
        w1f + (size_t)(n0 + (lane >> 2)) * KPAD + ((lane & 3) ^ ((lane >> 3) & 3)) * 8;

    const uint32_t* pbits = bits_t + m0 + l15;

    f32x4 acc[2][4][2];
    const f32x4 fz = {0.f, 0.f, 0.f, 0.f};
    #pragma unroll
    for (int t = 0; t < 2; ++t)
        #pragma unroll
        for (int mi = 0; mi < 4; ++mi)
            #pragma unroll
            for (int ni = 0; ni < 2; ++ni) acc[t][mi][ni] = fz;

    int boff[2];
    #pragma unroll
    for (int ni = 0; ni < 2; ++ni) {
        const int br = wave * 32 + ni * 16 + l15;
        boff[ni] = br * 16 + ((g ^ ((br >> 1) & 3)) << 2);
    }

#define STAGE_B(tt, bb)                                                        \
    {                                                                          \
        _Pragma("unroll")                                                      \
        for (int j = 0; j < 4; ++j) {                                          \
            const int e    = wave * 4 + j;    /* 0..15 */                      \
            const int term = e >> 3;                                           \
            const int ii   = e & 7;           /* 16-row slab */                \
            const unsigned short* src =                                        \
                bsrc0 + (size_t)(term * H1 + ii * 16) * KPAD + (size_t)(tt) * 32; \
            __builtin_amdgcn_global_load_lds(                                  \
                (const __attribute__((address_space(1))) uint32_t*)src,        \
                (__attribute__((address_space(3))) uint32_t*)&BsU[bb][term * 2048 + ii * 256], \
                16, 0, 0);                                                     \
        }                                                                      \
    }

#define LOAD_W(W, tt)                                                          \
    {                                                                          \
        const uint32_t* p = pbits + (size_t)(tt) * M_PADN;                     \
        _Pragma("unroll")                                                      \
        for (int mi = 0; mi < 4; ++mi) W[mi] = p[mi * 16];                     \
    }

#define COMPUTE(W, bb)                                                         \
    {                                                                          \
        half8 bf0[2], bf1[2];                                                  \
        _Pragma("unroll")                                                      \
        for (int ni = 0; ni < 2; ++ni) {                                       \
            bf0[ni] = *(const half8*)&BsU[bb][boff[ni]];                       \
            bf1[ni] = *(const half8*)&BsU[bb][2048 + boff[ni]];                \
        }                                                                      \
        __builtin_amdgcn_s_setprio(1);                                         \
        _Pragma("unroll")                                                      \
        for (int mi = 0; mi < 4; ++mi) {                                       \
            const uint32_t w8 = W[mi] >> (g * 8);                              \
            union { uint32_t u[4]; half8 h; } cv;                              \
            _Pragma("unroll")                                                  \
            for (int i = 0; i < 4; ++i)                                        \
                cv.u[i] = ((((w8 >> (2 * i)) & 3u) * 0x8001u) & 0x10001u)      \
                          * 0x3C00u;                                           \
            _Pragma("unroll")                                                  \
            for (int ni = 0; ni < 2; ++ni) {                                   \
                acc[0][mi][ni] = __builtin_amdgcn_mfma_f32_16x16x32_f16(       \
                    cv.h, bf0[ni], acc[0][mi][ni], 0, 0, 0);                   \
                acc[1][mi][ni] = __builtin_amdgcn_mfma_f32_16x16x32_f16(       \
                    cv.h, bf1[ni], acc[1][mi][ni], 0, 0, 0);                   \
            }                                                                  \
        }                                                                      \
        __builtin_amdgcn_s_setprio(0);                                         \
    }

#define ITER(tt, cb, WCUR, WNEXT)                                              \
    {                                                                          \
        LOAD_W(WNEXT, (tt) + 1);                                               \
        STAGE_B((tt) + 1, (cb) ^ 1);                                           \
        COMPUTE(WCUR, cb);                                                     \
        __syncthreads();                                                       \
    }

    uint32_t wA[4], wB[4];
    // ---- prologue: tile 0 into buf 0 ----
    LOAD_W(wA, 0);
    STAGE_B(0, 0);
    __syncthreads();

    // ---- main loop: t = 0..195 in pairs (stage/prefetch t+1) ----
    for (int t = 0; t < KW - 2; t += 2) {
        ITER(t,     0, wA, wB);
        ITER(t + 1, 1, wB, wA);
    }
    ITER(KW - 2, 0, wA, wB);      // t=196: stages 197 -> buf1, computes 196
    COMPUTE(wB, 1);               // tile 197

#undef ITER
#undef COMPUTE
#undef LOAD_W
#undef STAGE_B

    // ---- epilogue: D layout col=lane&15 (n), row=(lane>>4)*4+r (m) ----
    #pragma unroll
    for (int mi = 0; mi < 4; ++mi) {
        const int mbase = m0 + mi * 16 + g * 4;
        #pragma unroll
        for (int ni = 0; ni < 2; ++ni) {
            const int o = n0 + wave * 32 + ni * 16 + l15;
            #pragma unroll
            for (int r = 0; r < 4; ++r)
                u1[(size_t)(mbase + r) * H1 + o] =
                    acc[0][mi][ni][r] + acc[1][mi][ni][r] * INV2048;
        }
    }
}

// ---------------------------------------------------------------------------
// Kernel 3: fused psp1 + spike_dyn1 over T; writes s1 as fp16 (0 / 0x3C00)
// ---------------------------------------------------------------------------
__global__ void scan1_k(const float* __restrict__ u1, unsigned short* __restrict__ s1f) {
    const int lane = blockIdx.x * 64 + threadIdx.x;   // 0..16383 = b*1024+h
    const float CREF = -20.0f * CC_C;
    float p1 = 0.f, q1 = 0.f, pr = 0.f, qr = 0.f;
    float A[10], Bv[10];

#define STEP1(xv, tidx) {                                   \
        q1 = DD_C * (q1 + p1); p1 = DD_C * p1 + (xv);       \
        const float uu = CC_C * q1;                         \
        qr = DD_C * (qr + pr);                              \
        const float vv = uu + CREF * qr - THETA_C;          \
        const float ss = (vv >= 0.f) ? 1.f : 0.f;           \
        pr = DD_C * pr + ss;                                \
        s1f[(size_t)(tidx) * 16384 + lane] =                \
            (vv >= 0.f) ? (unsigned short)0x3C00 : (unsigned short)0; }

    #pragma unroll
    for (int j = 0; j < 10; ++j) A[j] = u1[(size_t)j * 16384 + lane];
    for (int it = 0; it < 25; ++it) {
        const int gB = 2 * it + 1;
        #pragma unroll
        for (int j = 0; j < 10; ++j) Bv[j] = u1[(size_t)(gB * 10 + j) * 16384 + lane];
        #pragma unroll
        for (int j = 0; j < 10; ++j) STEP1(A[j], (2 * it) * 10 + j);
        if (it < 24) {
            const int gA = 2 * it + 2;
            #pragma unroll
            for (int j = 0; j < 10; ++j) A[j] = u1[(size_t)(gA * 10 + j) * 16384 + lane];
        }
        #pragma unroll
        for (int j = 0; j < 10; ++j) STEP1(Bv[j], gB * 10 + j);
    }
#undef STEP1
}

// ---------------------------------------------------------------------------
// Kernel 4: GEMM2 via MFMA fp16, K-split x4: u2p[kc][m][32] partials.
// ---------------------------------------------------------------------------
__global__ __launch_bounds__(256)
void gemm2_mfma_k(const unsigned short* __restrict__ s1f,
                  const unsigned short* __restrict__ w2f,
                  float* __restrict__ u2p) {
    __shared__ uint32_t AsU[128 * 16];       // 8 KB : [row][16 u32]
    __shared__ uint32_t BsU[2 * 32 * 16];    // 4 KB : [term][o][16 u32]

    const int tid  = threadIdx.x;
    const int lane = tid & 63;
    const int wave = tid >> 6;
    const int m0 = blockIdx.x * 128;
    const int kc = blockIdx.y;               // 0..3
    const int l15 = lane & 15, g = lane >> 4;

    f32x4 acc[2][2][2];
    const f32x4 fz = {0.f, 0.f, 0.f, 0.f};
    #pragma unroll
    for (int t = 0; t < 2; ++t)
        #pragma unroll
        for (int i = 0; i < 2; ++i)
            #pragma unroll
            for (int j = 0; j < 2; ++j) acc[t][i][j] = fz;

    int aoff[2], boff[2][2];
    #pragma unroll
    for (int mi = 0; mi < 2; ++mi) {
        const int ar = wave * 32 + mi * 16 + l15;
        aoff[mi] = ar * 16 + ((g ^ ((ar >> 1) & 3)) << 2);
    }
    #pragma unroll
    for (int term = 0; term < 2; ++term)
        #pragma unroll
        for (int ni = 0; ni < 2; ++ni) {
            const int br = ni * 16 + l15;
            boff[term][ni] = term * 512 + br * 16 + ((g ^ ((br >> 1) & 3)) << 2);
        }

    for (int kw8 = 0; kw8 < 8; ++kw8) {
        const int kw = kc * 8 + kw8;
        __syncthreads();
        #pragma unroll
        for (int i = 0; i < 2; ++i) {
            const int c   = i * 256 + tid;          // 16B chunk id
            const int row = c >> 2;
            const int kch = c & 3;
            const unsigned short* src =
                s1f + (size_t)(m0 + row) * H1 + kw * 32 + (kch ^ ((row >> 1) & 3)) * 8;
            __builtin_amdgcn_global_load_lds(
                (const __attribute__((address_space(1))) uint32_t*)src,
                (__attribute__((address_space(3))) uint32_t*)&AsU[(i * 256 + wave * 64) * 4],
                16, 0, 0);
        }
        {
            const int c    = tid;                   // 0..255
            const int term = c >> 7;
            const int o    = (c >> 2) & 31;
            const int kch  = c & 3;
            const unsigned short* src =
                w2f + (size_t)(term * N2P + o) * H1 + kw * 32 + (kch ^ ((o >> 1) & 3)) * 8;
            __builtin_amdgcn_global_load_lds(
                (const __attribute__((address_space(1))) uint32_t*)src,
                (__attribute__((address_space(3))) uint32_t*)&BsU[wave * 256],
                16, 0, 0);
        }
        __syncthreads();

        half8 af[2];
        #pragma unroll
        for (int mi = 0; mi < 2; ++mi) af[mi] = *(const half8*)&AsU[aoff[mi]];
        #pragma unroll
        for (int term = 0; term < 2; ++term)
            #pragma unroll
            for (int ni = 0; ni < 2; ++ni) {
                const half8 bf = *(const half8*)&BsU[boff[term][ni]];
                #pragma unroll
                for (int mi = 0; mi < 2; ++mi)
                    acc[term][mi][ni] = __builtin_amdgcn_mfma_f32_16x16x32_f16(
                        af[mi], bf, acc[term][mi][ni], 0, 0, 0);
            }
    }

    #pragma unroll
    for (int mi = 0; mi < 2; ++mi) {
        const int mbase = m0 + wave * 32 + mi * 16 + g * 4;
        #pragma unroll
        for (int ni = 0; ni < 2; ++ni) {
            const int o = ni * 16 + l15;
            #pragma unroll
            for (int r = 0; r < 4; ++r)
                u2p[((size_t)kc * M_PADN + mbase + r) * N2P + o] =
                    acc[0][mi][ni][r] + acc[1][mi][ni][r] * INV2048;
        }
    }
}

// ---------------------------------------------------------------------------
// Kernel 4b: sum the 4 K-partials -> u2[m][32]
// ---------------------------------------------------------------------------
__global__ void sum_u2_k(const float* __restrict__ u2p, float* __restrict__ u2) {
    const int i = blockIdx.x * 256 + threadIdx.x;     // over M_PADN*N2P
    const size_t P = (size_t)M_PADN * N2P;
    u2[i] = (u2p[i] + u2p[P + i]) + (u2p[2 * P + i] + u2p[3 * P + i]);
}

// ---------------------------------------------------------------------------
// Kernel 5: fused psp2 + spike_dyn2 (320 lanes), single load per step.
// ---------------------------------------------------------------------------
__global__ void scan2_k(const float* __restrict__ u2, float* __restrict__ out) {
    const int lane = blockIdx.x * 64 + threadIdx.x;    // 0..319 = b*20 + o2
    if (lane >= 320) return;
    const int b  = lane / 20;
    const int o2 = lane % 20;
    const int boffs = b * N2P + o2;
    const float CREF = -20.0f * CC_C;
    float p1 = 0.f, q1 = 0.f, pr = 0.f, qr = 0.f;
    float A[10], Bv[10];

#define LOAD2(tidx) (u2[(size_t)(tidx) * 512 + boffs])

#define STEP2(xv, tidx) {                                   \
        q1 = DD_C * (q1 + p1); p1 = DD_C * p1 + (xv);       \
        const float uu = CC_C * q1;                         \
        qr = DD_C * (qr + pr);                              \
        const float vv = uu + CREF * qr - THETA_C;          \
        const float ss = (vv >= 0.f) ? 1.f : 0.f;           \
        pr = DD_C * pr + ss;                                \
        out[(size_t)lane * T_N + (tidx)] = ss; }

    #pragma unroll
    for (int j = 0; j < 10; ++j) A[j] = LOAD2(j);
    for (int it = 0; it < 25; ++it) {
        const int gB = 2 * it + 1;
        #pragma unroll
        for (int j = 0; j < 10; ++j) Bv[j] = LOAD2(gB * 10 + j);
        #pragma unroll
        for (int j = 0; j < 10; ++j) STEP2(A[j], (2 * it) * 10 + j);
        if (it < 24) {
            const int gA = 2 * it + 2;
            #pragma unroll
            for (int j = 0; j < 10; ++j) A[j] = LOAD2(gA * 10 + j);
        }
        #pragma unroll
        for (int j = 0; j < 10; ++j) STEP2(Bv[j], gB * 10 + j);
    }
#undef STEP2
#undef LOAD2
}

// ---------------------------------------------------------------------------
extern "C" void kernel_launch(void* const* d_in, const int* in_sizes, int n_in,
                              void* d_out, int out_size, void* d_ws, size_t ws_size,
                              hipStream_t stream) {
    const float* x  = (const float*)d_in[0];   // (16,2,50,63,500) binary
    const float* w1 = (const float*)d_in[1];   // (1024,6300)
    const float* w2 = (const float*)d_in[2];   // (20,1024)
    float* out = (float*)d_out;                // (16,20,500)

    char* ws = (char*)d_ws;
    size_t off = 0;
    uint32_t*       bits_t = (uint32_t*)(ws + off);       off += (size_t)KW * M_PADN * 4;       //  6.39 MB
    unsigned short* w1f    = (unsigned short*)(ws + off); off += (size_t)2 * H1 * KPAD * 2;     // 25.95 MB
    unsigned short* w2f    = (unsigned short*)(ws + off); off += (size_t)2 * N2P * H1 * 2;      //  0.13 MB
    float*          u1     = (float*)(ws + off);          off += (size_t)M_PADN * H1 * 4;       // 33.03 MB
    unsigned short* s1f    = (unsigned short*)(ws + off); off += (size_t)M_PADN * H1 * 2;       // 16.52 MB
    float*          u2p    = (float*)(ws + off);          off += (size_t)4 * M_PADN * N2P * 4;  //  4.13 MB
    float*          u2     = (float*)(ws + off);          off += (size_t)M_PADN * N2P * 4;      //  1.03 MB
    (void)ws_size; (void)in_sizes; (void)n_in; (void)out_size;

    prep_fused_k <<<7392,         256, 0, stream>>>(x, w1, w2, bits_t, w1f, w2f);
    gemm1_mfma_k <<<dim3(8, 126), 256, 0, stream>>>(bits_t, w1f, u1);
    scan1_k      <<<256,          64,  0, stream>>>(u1, s1f);
    gemm2_mfma_k <<<dim3(63, 4),  256, 0, stream>>>(s1f, w2f, u2p);
    sum_u2_k     <<<1008,         256, 0, stream>>>(u2p, u2);
    scan2_k      <<<5,            64,  0, stream>>>(u2, out);
}

// Round 12
// 312.392 us; speedup vs baseline: 1.2558x; 1.2558x over previous
//
#include <hip/hip_runtime.h>
#include <cstdint>
#include <cstddef>

// Problem geometry
#define T_N   500
#define B_N   16
#define F_IN  6300
#define KW    198          // 198 words * 32 bits = 6336 (K padded)
#define KPAD  6336
#define H1    1024
#define H2    20
#define N2P   32           // gemm2 N padded 20 -> 32
#define M_N   8000         // T*B rows, m = t*16 + b
#define M_PADN 8064        // 63 * 128

// SLAYER constants
#define DD_C   0.36787944117144233f   // exp(-1)
#define CC_C   2.718281828459045f     // e / tau
#define THETA_C 10.0f
#define INV2048 4.8828125e-4f

typedef _Float16 half8 __attribute__((ext_vector_type(8)));
typedef __attribute__((ext_vector_type(4))) float f32x4;

__device__ __forceinline__ unsigned short f2h_bits(float x) {
    union { _Float16 h; unsigned short u; } c; c.h = (_Float16)x; return c.u;
}
__device__ __forceinline__ float h2f(unsigned short u) {
    union { _Float16 h; unsigned short u; } c; c.u = u; return (float)c.h;
}

// ---------------------------------------------------------------------------
// Kernel 1 (fused prep):
//   [0,6336)    : pack input spikes -> bits_t[kw][m], m=(t*16+b)
//   [6336,7360) : split w1 -> w1f[2][1024][6336] fp16 (term2 scaled 2^11)
//   [7360,7392) : split w2 -> w2f[2][32][1024] fp16
// ---------------------------------------------------------------------------
__global__ void prep_fused_k(const float* __restrict__ x,
                             const float* __restrict__ w1,
                             const float* __restrict__ w2,
                             uint32_t* __restrict__ bits_t,
                             unsigned short* __restrict__ w1f,
                             unsigned short* __restrict__ w2f) {
    const int bid = blockIdx.x;
    if (bid < 6336) {
        const int b    = bid & 15;
        const int tmp  = bid >> 4;         // 0..395
        const int w    = tmp % 198;
        const int tch2 = tmp / 198;        // 0..1
        const int t    = tch2 * 256 + threadIdx.x;   // 0..511
        if (t >= 504) return;
        const int m = t * 16 + b;
        uint32_t word = 0u;
        if (t < T_N) {
            const int fbase = w * 32;
            #pragma unroll
            for (int j = 0; j < 32; ++j) {
                const int f = fbase + j;
                float v = 0.f;
                if (f < F_IN) v = x[((size_t)b * F_IN + f) * T_N + t];
                word |= (v != 0.f ? 1u : 0u) << j;
            }
        }
        bits_t[(size_t)w * M_PADN + m] = word;
    } else if (bid < 6336 + 1024) {
        const int o = bid - 6336;
        #pragma unroll 1
        for (int it = 0; it < 25; ++it) {
            const int f = it * 256 + threadIdx.x;
            if (f >= KPAD) break;
            float w = (f < F_IN) ? w1[(size_t)o * F_IN + f] : 0.f;
            const unsigned short h1 = f2h_bits(w);
            const float r1 = w - h2f(h1);
            const unsigned short h2 = f2h_bits(r1 * 2048.0f);
            const size_t base = (size_t)o * KPAD + f;
            w1f[base]                     = h1;
            w1f[(size_t)H1 * KPAD + base] = h2;
        }
    } else {
        const int o = bid - 7360;          // 0..31
        #pragma unroll
        for (int it = 0; it < 4; ++it) {
            const int k = it * 256 + threadIdx.x;
            float w = (o < H2) ? w2[(size_t)o * H1 + k] : 0.f;
            const unsigned short h1 = f2h_bits(w);
            const float r1 = w - h2f(h1);
            const unsigned short h2 = f2h_bits(r1 * 2048.0f);
            const size_t base = (size_t)o * H1 + k;
            w2f[base]                    = h1;
            w2f[(size_t)N2P * H1 + base] = h2;
        }
    }
}

// ---------------------------------------------------------------------------
// Kernel 2: GEMM1 via MFMA fp16 — ROUND-5 CONFIG VERBATIM (empirical best,
//   202 µs): block 128m x 128n, 2x2 wave grid, in-register A unpack from
//   bits_t, B-only LDS double-buffer with source-side chunk XOR (0 bank
//   conflicts), stage/prefetch depth 1, plain __syncthreads.
//   All deviations tried (B-read-once, counted vmcnt, small tiles) regressed.
// ---------------------------------------------------------------------------
__global__ __launch_bounds__(256, 2)
void gemm1_mfma_k(const uint32_t* __restrict__ bits_t,
                  const unsigned short* __restrict__ w1f,
                  float* __restrict__ u1) {
    __shared__ uint32_t BsU[2][2 * 128 * 16];    // 32 KB : [buf][term][row][16 u32]

    const int tid  = threadIdx.x;
    const int lane = tid & 63;
    const int wave = tid >> 6;
    const int wr = wave >> 1, wc = wave & 1;
    const int n0 = blockIdx.x * 128;          // n-tile -> XCD-exclusive B panel
    const int m0 = blockIdx.y * 128;
    const int l15 = lane & 15, g = lane >> 4;

    // B stage source: lane covers (row = lane>>2, chunk-pos = lane&3) of each
    // 16-row slab; source chunk = pos ^ ((row>>1)&3)  [(row>>1)&3 == (lane>>3)&3]
    const unsigned short* bsrc0 =
        w1f + (size_t)(n0 + (lane >> 2)) * KPAD + ((lane & 3) ^ ((lane >> 3) & 3)) * 8;

    // A bit-word pointer: 4 words per lane per K-step (rows wr*64 + mi*16 + l15)
    const uint32_t* pbits = bits_t + m0 + wr * 64 + l15;

    f32x4 acc[2][4][4];
    const f32x4 fz = {0.f, 0.f, 0.f, 0.f};
    #pragma unroll
    for (int t = 0; t < 2; ++t)
        #pragma unroll
        for (int i = 0; i < 4; ++i)
            #pragma unroll
            for (int j = 0; j < 4; ++j) acc[t][i][j] = fz;

    // B fragment LDS offsets (u32 units), conflict-free XOR
    int boff[4];
    #pragma unroll
    for (int ni = 0; ni < 4; ++ni) {
        const int br = wc * 64 + ni * 16 + l15;
        boff[ni] = br * 16 + ((g ^ ((br >> 1) & 3)) << 2);
    }

#define STAGE_B(tt, bb)                                                        \
    {                                                                          \
        _Pragma("unroll")                                                      \
        for (int j = 0; j < 4; ++j) {                                          \
            const int e    = wave * 4 + j;                                     \
            const int term = e >> 3;                                           \
            const int ii   = e & 7;                                            \
            const unsigned short* src =                                        \
                bsrc0 + (size_t)(term * H1 + ii * 16) * KPAD + (size_t)(tt) * 32; \
            __builtin_amdgcn_global_load_lds(                                  \
                (const __attribute__((address_space(1))) uint32_t*)src,        \
                (__attribute__((address_space(3))) uint32_t*)&BsU[bb][term * 2048 + ii * 256], \
                16, 0, 0);                                                     \
        }                                                                      \
    }

#define LOAD_W(W, tt)                                                          \
    {                                                                          \
        _Pragma("unroll")                                                      \
        for (int mi = 0; mi < 4; ++mi)                                         \
            W[mi] = pbits[(size_t)(tt) * M_PADN + mi * 16];                    \
    }

#define COMPUTE(W, bb)                                                         \
    {                                                                          \
        half8 af[4];                                                           \
        _Pragma("unroll")                                                      \
        for (int mi = 0; mi < 4; ++mi) {                                       \
            union { uint32_t u[4]; half8 h; } cv;                              \
            _Pragma("unroll")                                                  \
            for (int i = 0; i < 4; ++i) {                                      \
                const int b0 = g * 8 + 2 * i;                                  \
                cv.u[i] = (((W[mi] >> b0) & 1u) ? 0x00003C00u : 0u) |          \
                          (((W[mi] >> (b0 + 1)) & 1u) ? 0x3C000000u : 0u);     \
            }                                                                  \
            af[mi] = cv.h;                                                     \
        }                                                                      \
        __builtin_amdgcn_s_setprio(1);                                         \
        _Pragma("unroll")                                                      \
        for (int term = 0; term < 2; ++term) {                                 \
            half8 bfv[4];                                                      \
            _Pragma("unroll")                                                  \
            for (int ni = 0; ni < 4; ++ni)                                     \
                bfv[ni] = *(const half8*)&BsU[bb][term * 2048 + boff[ni]];     \
            _Pragma("unroll")                                                  \
            for (int mi = 0; mi < 4; ++mi)                                     \
                _Pragma("unroll")                                              \
                for (int ni = 0; ni < 4; ++ni)                                 \
                    acc[term][mi][ni] = __builtin_amdgcn_mfma_f32_16x16x32_f16( \
                        af[mi], bfv[ni], acc[term][mi][ni], 0, 0, 0);          \
        }                                                                      \
        __builtin_amdgcn_s_setprio(0);                                         \
    }

#define ITER(tt, cb, WCUR, WNEXT)                                              \
    {                                                                          \
        LOAD_W(WNEXT, (tt) + 1);                                               \
        STAGE_B((tt) + 1, (cb) ^ 1);                                           \
        COMPUTE(WCUR, cb);                                                     \
        __syncthreads();                                                       \
    }

    uint32_t wA[4], wB[4];
    // ---- prologue: tile 0 into buf 0 ----
    LOAD_W(wA, 0);
    STAGE_B(0, 0);
    __syncthreads();

    // ---- main loop: t = 0..195 in pairs (stage t+1, compute t) ----
    for (int t = 0; t < KW - 2; t += 2) {
        ITER(t,     0, wA, wB);
        ITER(t + 1, 1, wB, wA);
    }
    ITER(KW - 2, 0, wA, wB);      // t=196: stages 197 -> buf1, computes 196
    COMPUTE(wB, 1);               // tile 197

#undef ITER
#undef COMPUTE
#undef LOAD_W
#undef STAGE_B

    // ---- epilogue: D layout col=lane&15, row=(lane>>4)*4+r ----
    #pragma unroll
    for (int mi = 0; mi < 4; ++mi) {
        const int mbase = m0 + wr * 64 + mi * 16 + g * 4;
        #pragma unroll
        for (int ni = 0; ni < 4; ++ni) {
            const int o = n0 + wc * 64 + ni * 16 + l15;
            #pragma unroll
            for (int r = 0; r < 4; ++r)
                u1[(size_t)(mbase + r) * H1 + o] =
                    acc[0][mi][ni][r] + acc[1][mi][ni][r] * INV2048;
        }
    }
}

// ---------------------------------------------------------------------------
// Kernel 3: fused psp1 + spike_dyn1 over T; writes s1 as fp16 (0 / 0x3C00)
// ---------------------------------------------------------------------------
__global__ void scan1_k(const float* __restrict__ u1, unsigned short* __restrict__ s1f) {
    const int lane = blockIdx.x * 64 + threadIdx.x;   // 0..16383 = b*1024+h
    const float CREF = -20.0f * CC_C;
    float p1 = 0.f, q1 = 0.f, pr = 0.f, qr = 0.f;
    float A[10], Bv[10];

#define STEP1(xv, tidx) {                                   \
        q1 = DD_C * (q1 + p1); p1 = DD_C * p1 + (xv);       \
        const float uu = CC_C * q1;                         \
        qr = DD_C * (qr + pr);                              \
        const float vv = uu + CREF * qr - THETA_C;          \
        const float ss = (vv >= 0.f) ? 1.f : 0.f;           \
        pr = DD_C * pr + ss;                                \
        s1f[(size_t)(tidx) * 16384 + lane] =                \
            (vv >= 0.f) ? (unsigned short)0x3C00 : (unsigned short)0; }

    #pragma unroll
    for (int j = 0; j < 10; ++j) A[j] = u1[(size_t)j * 16384 + lane];
    for (int it = 0; it < 25; ++it) {
        const int gB = 2 * it + 1;
        #pragma unroll
        for (int j = 0; j < 10; ++j) Bv[j] = u1[(size_t)(gB * 10 + j) * 16384 + lane];
        #pragma unroll
        for (int j = 0; j < 10; ++j) STEP1(A[j], (2 * it) * 10 + j);
        if (it < 24) {
            const int gA = 2 * it + 2;
            #pragma unroll
            for (int j = 0; j < 10; ++j) A[j] = u1[(size_t)(gA * 10 + j) * 16384 + lane];
        }
        #pragma unroll
        for (int j = 0; j < 10; ++j) STEP1(Bv[j], gB * 10 + j);
    }
#undef STEP1
}

// ---------------------------------------------------------------------------
// Kernel 4: GEMM2 via MFMA fp16, K-split x4: u2p[kc][m][32] partials.
// ---------------------------------------------------------------------------
__global__ __launch_bounds__(256)
void gemm2_mfma_k(const unsigned short* __restrict__ s1f,
                  const unsigned short* __restrict__ w2f,
                  float* __restrict__ u2p) {
    __shared__ uint32_t AsU[128 * 16];       // 8 KB : [row][16 u32]
    __shared__ uint32_t BsU[2 * 32 * 16];    // 4 KB : [term][o][16 u32]

    const int tid  = threadIdx.x;
    const int lane = tid & 63;
    const int wave = tid >> 6;
    const int m0 = blockIdx.x * 128;
    const int kc = blockIdx.y;               // 0..3
    const int l15 = lane & 15, g = lane >> 4;

    f32x4 acc[2][2][2];
    const f32x4 fz = {0.f, 0.f, 0.f, 0.f};
    #pragma unroll
    for (int t = 0; t < 2; ++t)
        #pragma unroll
        for (int i = 0; i < 2; ++i)
            #pragma unroll
            for (int j = 0; j < 2; ++j) acc[t][i][j] = fz;

    int aoff[2], boff[2][2];
    #pragma unroll
    for (int mi = 0; mi < 2; ++mi) {
        const int ar = wave * 32 + mi * 16 + l15;
        aoff[mi] = ar * 16 + ((g ^ ((ar >> 1) & 3)) << 2);
    }
    #pragma unroll
    for (int term = 0; term < 2; ++term)
        #pragma unroll
        for (int ni = 0; ni < 2; ++ni) {
            const int br = ni * 16 + l15;
            boff[term][ni] = term * 512 + br * 16 + ((g ^ ((br >> 1) & 3)) << 2);
        }

    for (int kw8 = 0; kw8 < 8; ++kw8) {
        const int kw = kc * 8 + kw8;
        __syncthreads();
        #pragma unroll
        for (int i = 0; i < 2; ++i) {
            const int c   = i * 256 + tid;          // 16B chunk id
            const int row = c >> 2;
            const int kch = c & 3;
            const unsigned short* src =
                s1f + (size_t)(m0 + row) * H1 + kw * 32 + (kch ^ ((row >> 1) & 3)) * 8;
            __builtin_amdgcn_global_load_lds(
                (const __attribute__((address_space(1))) uint32_t*)src,
                (__attribute__((address_space(3))) uint32_t*)&AsU[(i * 256 + wave * 64) * 4],
                16, 0, 0);
        }
        {
            const int c    = tid;                   // 0..255
            const int term = c >> 7;
            const int o    = (c >> 2) & 31;
            const int kch  = c & 3;
            const unsigned short* src =
                w2f + (size_t)(term * N2P + o) * H1 + kw * 32 + (kch ^ ((o >> 1) & 3)) * 8;
            __builtin_amdgcn_global_load_lds(
                (const __attribute__((address_space(1))) uint32_t*)src,
                (__attribute__((address_space(3))) uint32_t*)&BsU[wave * 256],
                16, 0, 0);
        }
        __syncthreads();

        half8 af[2];
        #pragma unroll
        for (int mi = 0; mi < 2; ++mi) af[mi] = *(const half8*)&AsU[aoff[mi]];
        #pragma unroll
        for (int term = 0; term < 2; ++term)
            #pragma unroll
            for (int ni = 0; ni < 2; ++ni) {
                const half8 bf = *(const half8*)&BsU[boff[term][ni]];
                #pragma unroll
                for (int mi = 0; mi < 2; ++mi)
                    acc[term][mi][ni] = __builtin_amdgcn_mfma_f32_16x16x32_f16(
                        af[mi], bf, acc[term][mi][ni], 0, 0, 0);
            }
    }

    #pragma unroll
    for (int mi = 0; mi < 2; ++mi) {
        const int mbase = m0 + wave * 32 + mi * 16 + g * 4;
        #pragma unroll
        for (int ni = 0; ni < 2; ++ni) {
            const int o = ni * 16 + l15;
            #pragma unroll
            for (int r = 0; r < 4; ++r)
                u2p[((size_t)kc * M_PADN + mbase + r) * N2P + o] =
                    acc[0][mi][ni][r] + acc[1][mi][ni][r] * INV2048;
        }
    }
}

// ---------------------------------------------------------------------------
// Kernel 4b: sum the 4 K-partials -> u2[m][32]
// ---------------------------------------------------------------------------
__global__ void sum_u2_k(const float* __restrict__ u2p, float* __restrict__ u2) {
    const int i = blockIdx.x * 256 + threadIdx.x;     // over M_PADN*N2P
    const size_t P = (size_t)M_PADN * N2P;
    u2[i] = (u2p[i] + u2p[P + i]) + (u2p[2 * P + i] + u2p[3 * P + i]);
}

// ---------------------------------------------------------------------------
// Kernel 5: fused psp2 + spike_dyn2 (320 lanes), single load per step.
// ---------------------------------------------------------------------------
__global__ void scan2_k(const float* __restrict__ u2, float* __restrict__ out) {
    const int lane = blockIdx.x * 64 + threadIdx.x;    // 0..319 = b*20 + o2
    if (lane >= 320) return;
    const int b  = lane / 20;
    const int o2 = lane % 20;
    const int boffs = b * N2P + o2;
    const float CREF = -20.0f * CC_C;
    float p1 = 0.f, q1 = 0.f, pr = 0.f, qr = 0.f;
    float A[10], Bv[10];

#define LOAD2(tidx) (u2[(size_t)(tidx) * 512 + boffs])

#define STEP2(xv, tidx) {                                   \
        q1 = DD_C * (q1 + p1); p1 = DD_C * p1 + (xv);       \
        const float uu = CC_C * q1;                         \
        qr = DD_C * (qr + pr);                              \
        const float vv = uu + CREF * qr - THETA_C;          \
        const float ss = (vv >= 0.f) ? 1.f : 0.f;           \
        pr = DD_C * pr + ss;                                \
        out[(size_t)lane * T_N + (tidx)] = ss; }

    #pragma unroll
    for (int j = 0; j < 10; ++j) A[j] = LOAD2(j);
    for (int it = 0; it < 25; ++it) {
        const int gB = 2 * it + 1;
        #pragma unroll
        for (int j = 0; j < 10; ++j) Bv[j] = LOAD2(gB * 10 + j);
        #pragma unroll
        for (int j = 0; j < 10; ++j) STEP2(A[j], (2 * it) * 10 + j);
        if (it < 24) {
            const int gA = 2 * it + 2;
            #pragma unroll
            for (int j = 0; j < 10; ++j) A[j] = LOAD2(gA * 10 + j);
        }
        #pragma unroll
        for (int j = 0; j < 10; ++j) STEP2(Bv[j], gB * 10 + j);
    }
#undef STEP2
#undef LOAD2
}

// ---------------------------------------------------------------------------
extern "C" void kernel_launch(void* const* d_in, const int* in_sizes, int n_in,
                              void* d_out, int out_size, void* d_ws, size_t ws_size,
                              hipStream_t stream) {
    const float* x  = (const float*)d_in[0];   // (16,2,50,63,500) binary
    const float* w1 = (const float*)d_in[1];   // (1024,6300)
    const float* w2 = (const float*)d_in[2];   // (20,1024)
    float* out = (float*)d_out;                // (16,20,500)

    char* ws = (char*)d_ws;
    size_t off = 0;
    uint32_t*       bits_t = (uint32_t*)(ws + off);       off += (size_t)KW * M_PADN * 4;       //  6.39 MB
    unsigned short* w1f    = (unsigned short*)(ws + off); off += (size_t)2 * H1 * KPAD * 2;     // 25.95 MB
    unsigned short* w2f    = (unsigned short*)(ws + off); off += (size_t)2 * N2P * H1 * 2;      //  0.13 MB
    float*          u1     = (float*)(ws + off);          off += (size_t)M_PADN * H1 * 4;       // 33.03 MB
    unsigned short* s1f    = (unsigned short*)(ws + off); off += (size_t)M_PADN * H1 * 2;       // 16.52 MB
    float*          u2p    = (float*)(ws + off);          off += (size_t)4 * M_PADN * N2P * 4;  //  4.13 MB
    float*          u2     = (float*)(ws + off);          off += (size_t)M_PADN * N2P * 4;      //  1.03 MB
    (void)ws_size; (void)in_sizes; (void)n_in; (void)out_size;

    prep_fused_k <<<7392,        256, 0, stream>>>(x, w1, w2, bits_t, w1f, w2f);
    gemm1_mfma_k <<<dim3(8, 63), 256, 0, stream>>>(bits_t, w1f, u1);
    scan1_k      <<<256,         64,  0, stream>>>(u1, s1f);
    gemm2_mfma_k <<<dim3(63, 4), 256, 0, stream>>>(s1f, w2f, u2p);
    sum_u2_k     <<<1008,        256, 0, stream>>>(u2p, u2);
    scan2_k      <<<5,           64,  0, stream>>>(u2, out);
}